// Round 7
// baseline (340.710 us; speedup 1.0000x reference)
//
#include <hip/hip_runtime.h>
#include <math.h>

// [B=2, 1, D=192, H=192, W=192] fp32
#define W 192
#define H 192
#define DEPTH 192
#define BATCH 2
#define DC 6                   // output planes per block-chunk (more blocks = more TLP)
#define HW (H * W)
#define VOL ((size_t)DEPTH * HW)
#define ROWT 48                // threads per H-row, 4 cols each -> full W
#define ROWSB 4                // H-rows per block
#define BLOCKT (ROWT * ROWSB)  // 192 threads = 3 waves
#define ROUNDS (DC + 2)        // planes d0-1 .. d0+DC

// No-LDS, no-barrier streaming 2.5D stencil with EXPLICIT register
// double-buffer prefetch: iter t issues plane t+1's loads into buf t^1,
// then computes plane t from buf t&1. WAR on the ping-pong registers
// throttles the pipe to depth 2; compiler emits partial vmcnt waits, so
// every load has a full compute phase of slack. No barriers anywhere.

__global__ __launch_bounds__(BLOCKT, 3) void sobel_loss_part(
    const float* __restrict__ pred, const float* __restrict__ gt,
    const float* __restrict__ mask, float* __restrict__ partials)
{
    const int tid = threadIdx.x;
    const int rt = tid / ROWT;          // row in block 0..3
    const int ct = tid - rt * ROWT;     // col group 0..47
    const int wc = 4 * ct;
    const int h  = blockIdx.x * ROWSB + rt;
    const int d0 = blockIdx.y * DC;
    const size_t base = (size_t)blockIdx.z * VOL;

    const bool lok = (wc > 0), rok = (wc + 4 < W);
    const bool y0ok = (h > 0), y2ok = (h + 1 < H);
    const int g1 = h * W + wc;          // middle row, within-plane offset
    const int g0 = g1 - W, g2 = g1 + W;

    // double-buffered register plane: [buf][array]
    float4 Rm0[2][2], Rm1[2][2], Rm2[2][2];
    float  Rl0[2][2], Rl1[2][2], Rl2[2][2];
    float  Rr0[2][2], Rr1[2][2], Rr2[2][2];

    auto load_plane = [&](int p, int buf) {
        const bool pv = (p >= 0) && (p < DEPTH);
        const size_t pb = base + (size_t)(pv ? p : 0) * HW;
        #pragma unroll
        for (int a = 0; a < 2; ++a) {
            const float* __restrict__ s = a ? gt : pred;
            const bool b0 = pv && y0ok, b1 = pv, b2 = pv && y2ok;
            Rm0[buf][a] = b0 ? *(const float4*)(s + pb + g0) : make_float4(0,0,0,0);
            Rm1[buf][a] = b1 ? *(const float4*)(s + pb + g1) : make_float4(0,0,0,0);
            Rm2[buf][a] = b2 ? *(const float4*)(s + pb + g2) : make_float4(0,0,0,0);
            Rl0[buf][a] = (b0 && lok) ? s[pb + g0 - 1] : 0.f;
            Rl1[buf][a] = (b1 && lok) ? s[pb + g1 - 1] : 0.f;
            Rl2[buf][a] = (b2 && lok) ? s[pb + g2 - 1] : 0.f;
            Rr0[buf][a] = (b0 && rok) ? s[pb + g0 + 4] : 0.f;
            Rr1[buf][a] = (b1 && rok) ? s[pb + g1 + 4] : 0.f;
            Rr2[buf][a] = (b2 && rok) ? s[pb + g2 + 4] : 0.f;
        }
    };

    // pending D-combine accumulators [array][col]
    float AX[2][4], BX[2][4], AY[2][4], BY[2][4], AZ[2][4], BZ[2][4];
    #pragma unroll
    for (int a = 0; a < 2; ++a)
        #pragma unroll
        for (int c = 0; c < 4; ++c) {
            AX[a][c]=BX[a][c]=AY[a][c]=BY[a][c]=AZ[a][c]=BZ[a][c]=0.f;
        }

    float Pc[4] = {0,0,0,0}, Gc[4] = {0,0,0,0};   // centers of plane p-1
    float4 Mn = make_float4(0,0,0,0), Mc;
    float acc = 0.f;

    load_plane(d0 - 1, 0);              // prologue: fill buf 0

    #pragma unroll 2
    for (int t = 0; t < ROUNDS; ++t) {
        const int buf = t & 1;          // compile-time under unroll 2

        // 1) issue next plane's loads into the other buffer (no wait here)
        if (t + 1 < ROUNDS) load_plane(d0 + t, buf ^ 1);

        // 2) mask prefetch for next iteration's epilogue (output plane d0+t-1)
        Mc = Mn;
        if (t >= 1 && t <= DC)
            Mn = *(const float4*)(mask + base + (size_t)(d0 + t - 1) * HW + g1);

        const int p = d0 - 1 + t;
        float outx[2][4], outy[2][4], outz[2][4];
        float mid[2][4];

        // 3) compute plane p from buf (vmcnt wait lands here, one iter of slack)
        #pragma unroll
        for (int a = 0; a < 2; ++a) {
            float4 m0 = Rm0[buf][a], m1 = Rm1[buf][a], m2 = Rm2[buf][a];
            float v[3][6];
            v[0][0]=Rl0[buf][a]; v[0][5]=Rr0[buf][a];
            v[1][0]=Rl1[buf][a]; v[1][5]=Rr1[buf][a];
            v[2][0]=Rl2[buf][a]; v[2][5]=Rr2[buf][a];
            v[0][1]=m0.x; v[0][2]=m0.y; v[0][3]=m0.z; v[0][4]=m0.w;
            v[1][1]=m1.x; v[1][2]=m1.y; v[1][3]=m1.z; v[1][4]=m1.w;
            v[2][1]=m2.x; v[2][2]=m2.y; v[2][3]=m2.z; v[2][4]=m2.w;
            mid[a][0]=m1.x; mid[a][1]=m1.y; mid[a][2]=m1.z; mid[a][3]=m1.w;

            float sh[3][4], dh[3][4];
            #pragma unroll
            for (int r = 0; r < 3; ++r)
                #pragma unroll
                for (int c = 0; c < 4; ++c) {
                    sh[r][c] = v[r][c] + 2.f * v[r][c+1] + v[r][c+2];
                    dh[r][c] = v[r][c+2] - v[r][c];
                }
            #pragma unroll
            for (int c = 0; c < 4; ++c) {
                float qdx = dh[0][c] + 2.f * dh[1][c] + dh[2][c];  // s_h d_w
                float qsx = sh[0][c] + 2.f * sh[1][c] + sh[2][c];  // s_h s_w
                float qdy = sh[0][c] - sh[2][c];                   // d_h s_w
                outx[a][c] = AX[a][c] + qdx;             // gx(p-1) complete
                AX[a][c]   = fmaf(2.f, qdx, BX[a][c]);
                BX[a][c]   = qdx;
                outy[a][c] = AY[a][c] + qdy;             // gy(p-1)
                AY[a][c]   = fmaf(2.f, qdy, BY[a][c]);
                BY[a][c]   = qdy;
                outz[a][c] = AZ[a][c] - qsx;             // gz(p-1)=asx(p-2)-asx(p)
                AZ[a][c]   = BZ[a][c];
                BZ[a][c]   = qsx;
            }
        }

        // 4) epilogue for output plane od = p-1 (mask/centers prefetched)
        if (t >= 2) {
            const float mv[4] = {Mc.x, Mc.y, Mc.z, Mc.w};
            #pragma unroll
            for (int c = 0; c < 4; ++c) {
                float ga = __builtin_amdgcn_sqrtf(
                    fmaf(outz[0][c], outz[0][c],
                    fmaf(outy[0][c], outy[0][c],
                    fmaf(outx[0][c], outx[0][c], 1e-10f))));
                float gb = __builtin_amdgcn_sqrtf(
                    fmaf(outz[1][c], outz[1][c],
                    fmaf(outy[1][c], outy[1][c],
                    fmaf(outx[1][c], outx[1][c], 1e-10f))));
                float m   = mv[c];
                float dm  = Pc[c] - Gc[c];
                float mse = dm * dm * m;
                float dg  = gb - ga;
                float mge = dg * dg * m;
                // 1 + tanh(x) = 2 - 2*rcp(e^{2x}+1), x >= 0; saturates inf->rcp->0
                float ex = __expf(mge + mge);
                float rc = __builtin_amdgcn_rcpf(ex + 1.f);
                acc = fmaf(mse, fmaf(-2.f, rc, 2.f), acc);
            }
        }

        // 5) centers of plane p become "plane p-1 centers" next iter
        #pragma unroll
        for (int c = 0; c < 4; ++c) { Pc[c] = mid[0][c]; Gc[c] = mid[1][c]; }
    }

    // block reduction: 3 waves
    float v = acc;
    #pragma unroll
    for (int o = 32; o > 0; o >>= 1) v += __shfl_down(v, o, 64);
    __shared__ float red[3];
    if ((tid & 63) == 0) red[tid >> 6] = v;
    __syncthreads();
    if (tid == 0) {
        partials[(size_t)blockIdx.z * (gridDim.x * gridDim.y)
                 + (size_t)blockIdx.y * gridDim.x + blockIdx.x]
            = red[0] + red[1] + red[2];
    }
}

__global__ __launch_bounds__(256) void reduce_final(
    const float* __restrict__ partials, int n, float* __restrict__ out)
{
    int tid = threadIdx.x;
    double s = 0.0;
    for (int i = tid; i < n; i += 256) s += (double)partials[i];
    #pragma unroll
    for (int o = 32; o > 0; o >>= 1) s += __shfl_down(s, o, 64);
    __shared__ double red[4];
    if ((tid & 63) == 0) red[tid >> 6] = s;
    __syncthreads();
    if (tid == 0) {
        double t = red[0] + red[1] + red[2] + red[3];
        const double ntot = (double)BATCH * (double)DEPTH * (double)H * (double)W;
        out[0] = (float)(t / ntot);
    }
}

extern "C" void kernel_launch(void* const* d_in, const int* in_sizes, int n_in,
                              void* d_out, int out_size, void* d_ws, size_t ws_size,
                              hipStream_t stream) {
    const float* pred = (const float*)d_in[0];
    const float* gt   = (const float*)d_in[1];
    const float* mask = (const float*)d_in[2];
    float* partials = (float*)d_ws;

    dim3 grid(H / ROWSB, DEPTH / DC, BATCH);   // 48 x 32 x 2 = 3072 blocks
    sobel_loss_part<<<grid, BLOCKT, 0, stream>>>(pred, gt, mask, partials);

    int nparts = grid.x * grid.y * grid.z;
    reduce_final<<<1, 256, 0, stream>>>(partials, nparts, (float*)d_out);
}